// Round 2
// baseline (102.191 us; speedup 1.0000x reference)
//
#include <hip/hip_runtime.h>
#include <math.h>

// HAKE scoring kernel for MI355X — round 2.
// B=32, N=20000, D=256. out[b*N+n] = sigmoid(12 - (sum_d|sin(dphase/2)|*pw + ||r||*mw)).
// R1 lesson: 625-block grid left 2.44 blocks/CU resident (occupancy 18.8%,
// VALUBusy 45%). Now: 1 tile/block, 2500 blocks, __launch_bounds__(256,6)
// -> 6 blocks/CU co-resident, latency hidden.

#define B_      32
#define D_      256
#define N_      20000
#define NT      8                  // tail rows per tile
#define NBLOCKS (N_ / NT)          // 2500

// combined scale: x/(EMB_RANGE/PI) then /2 then rad->rev (/2pi) = x/(4*EMB_RANGE)
#define K2 4.571428571428571f

__device__ __forceinline__ float fract_(float x) { return __builtin_amdgcn_fractf(x); }
__device__ __forceinline__ float sinrev_(float x) { return __builtin_amdgcn_sinf(x); }

__global__ __launch_bounds__(256, 6)
void hake_kernel(const int* __restrict__ e1, const int* __restrict__ rel,
                 const float* __restrict__ emb_e, const float* __restrict__ emb_rel,
                 const float* __restrict__ pw_p, const float* __restrict__ mw_p,
                 float* __restrict__ out)
{
    __shared__ float2 tail[NT][D_];        // (phase_tail_rev, mod_tail) : 16 KB
    __shared__ float  red[4][2 * NT][32];  // per-wave partials          :  8 KB

    const int t = threadIdx.x;
    const int b = t & 31;     // batch index owned by this lane
    const int g = t >> 5;     // d-group 0..7 (also tile-row / out-n role)
    const int d_lo = g * 32;

    const float pw = pw_p[0];
    const float mw = mw_p[0];

    const int n0 = blockIdx.x * NT;

    // ---- stage 8 tail rows early (coalesced float4), overlap with table ----
    const float* rowp = emb_e + (size_t)(n0 + g) * (2 * D_);
    float4 p0 = *(const float4*)(rowp + b * 4);
    float4 p1 = *(const float4*)(rowp + 128 + b * 4);
    float4 m0 = *(const float4*)(rowp + 256 + b * 4);
    float4 m1 = *(const float4*)(rowp + 384 + b * 4);

    // ---- per-thread tables for (b, d in [d_lo, d_lo+32)) -------------------
    float ar[32], mh[32], cc[32];
    {
        const int he = e1[b];
        const int hr = rel[b];
        const float* be = emb_e + (size_t)he * (2 * D_);
        const float* br = emb_rel + (size_t)hr * (3 * D_);
#pragma unroll
        for (int ii = 0; ii < 8; ++ii) {
            float4 ph4 = *(const float4*)(be + d_lo + ii * 4);
            float4 mh4 = *(const float4*)(be + D_ + d_lo + ii * 4);
            float4 pr4 = *(const float4*)(br + d_lo + ii * 4);
            float4 mr4 = *(const float4*)(br + D_ + d_lo + ii * 4);
            float4 bi4 = *(const float4*)(br + 2 * D_ + d_lo + ii * 4);
            float phv[4] = {ph4.x, ph4.y, ph4.z, ph4.w};
            float mhv[4] = {mh4.x, mh4.y, mh4.z, mh4.w};
            float prv[4] = {pr4.x, pr4.y, pr4.z, pr4.w};
            float mrv[4] = {mr4.x, mr4.y, mr4.z, mr4.w};
            float biv[4] = {bi4.x, bi4.y, bi4.z, bi4.w};
#pragma unroll
            for (int k = 0; k < 4; ++k) {
                const int i = ii * 4 + k;
                float mr = fabsf(mrv[k]);
                float bi = fminf(biv[k], 1.0f);
                bi = (bi < -mr) ? -mr : bi;
                ar[i] = (phv[k] + prv[k]) * K2;   // revolutions for sin(x/2)
                mh[i] = mhv[k] * (mr + bi);
                cc[i] = 1.0f - bi;
            }
        }
    }

    // ---- write staged tail rows to LDS -------------------------------------
    {
        const int d0 = b * 4;
        tail[g][d0 + 0]       = make_float2(p0.x * K2, m0.x);
        tail[g][d0 + 1]       = make_float2(p0.y * K2, m0.y);
        tail[g][d0 + 2]       = make_float2(p0.z * K2, m0.z);
        tail[g][d0 + 3]       = make_float2(p0.w * K2, m0.w);
        tail[g][128 + d0 + 0] = make_float2(p1.x * K2, m1.x);
        tail[g][128 + d0 + 1] = make_float2(p1.y * K2, m1.y);
        tail[g][128 + d0 + 2] = make_float2(p1.z * K2, m1.z);
        tail[g][128 + d0 + 3] = make_float2(p1.w * K2, m1.w);
    }
    __syncthreads();

    // ---- accumulate: 32 d x 8 n per thread ---------------------------------
    float sph[NT], srs[NT];
#pragma unroll
    for (int j = 0; j < NT; ++j) { sph[j] = 0.0f; srs[j] = 0.0f; }

    const float4* tl = (const float4*)(&tail[0][0]);
#pragma unroll
    for (int i = 0; i < 32; i += 2) {
        const int d = d_lo + i;
#pragma unroll
        for (int j = 0; j < NT; ++j) {
            float4 tv = tl[(j * D_ + d) >> 1];  // (pt0,mt0,pt1,mt1) broadcast in group
            float a0 = ar[i] - tv.x;
            float s0 = sinrev_(fract_(a0));
            sph[j] += fabsf(s0);
            float r0 = fmaf(-tv.y, cc[i], mh[i]);
            srs[j] = fmaf(r0, r0, srs[j]);
            float a1 = ar[i + 1] - tv.z;
            float s1 = sinrev_(fract_(a1));
            sph[j] += fabsf(s1);
            float r1 = fmaf(-tv.w, cc[i + 1], mh[i + 1]);
            srs[j] = fmaf(r1, r1, srs[j]);
        }
    }

    // ---- reduce across the 8 d-groups --------------------------------------
    const int wv = t >> 6;
    const int lane = t & 63;
#pragma unroll
    for (int j = 0; j < NT; ++j) {
        sph[j] += __shfl_xor(sph[j], 32, 64);
        srs[j] += __shfl_xor(srs[j], 32, 64);
    }
    if (lane < 32) {
#pragma unroll
        for (int j = 0; j < NT; ++j) {
            red[wv][j][lane]      = sph[j];
            red[wv][NT + j][lane] = srs[j];
        }
    }
    __syncthreads();

    // ---- finalize: thread -> (b, n0+g) -------------------------------------
    {
        float pa = red[0][g][b] + red[1][g][b] + red[2][g][b] + red[3][g][b];
        float ra = red[0][NT + g][b] + red[1][NT + g][b] +
                   red[2][NT + g][b] + red[3][NT + g][b];
        float z = fmaf(pa, pw, sqrtf(ra) * mw) - 12.0f;  // GAMMA=12
        out[(size_t)b * N_ + (n0 + g)] = 1.0f / (1.0f + __expf(z));
    }
}

extern "C" void kernel_launch(void* const* d_in, const int* in_sizes, int n_in,
                              void* d_out, int out_size, void* d_ws, size_t ws_size,
                              hipStream_t stream)
{
    // inputs: 0:g 1:e1 2:rel 3:e2_multi(unused) 4:emb_e 5:emb_rel 6:phase_w 7:mod_w
    const int*   e1      = (const int*)d_in[1];
    const int*   rel     = (const int*)d_in[2];
    const float* emb_e   = (const float*)d_in[4];
    const float* emb_rel = (const float*)d_in[5];
    const float* pw      = (const float*)d_in[6];
    const float* mw      = (const float*)d_in[7];
    float* out = (float*)d_out;

    hipLaunchKernelGGL(hake_kernel, dim3(NBLOCKS), dim3(256), 0, stream,
                       e1, rel, emb_e, emb_rel, pw, mw, out);
}

// Round 3
// 57.915 us; speedup vs baseline: 1.7645x; 1.7645x over previous
//
#include <hip/hip_runtime.h>
#include <math.h>

// HAKE scoring kernel for MI355X — round 3.
// B=32, N=20000, D=256. out[b*N+n] = sigmoid(12 - (sum_d|sin(dphase/2)|*pw + ||r||*mw)).
// R2 lesson: launch_bounds(256,6) forced the 96-float per-thread tables to
// spill to scratch (FETCH 21->129 MB, VALUBusy 24%). Structural fix: split d
// across 2x threads. 512-thread blocks, 16 d-groups x 16 d -> tables = 48
// regs/thread, no spill at a relaxed (512,4) cap. Grid stays 2500 (1 tile/blk).

#define B_      32
#define D_      256
#define N_      20000
#define NT      8                  // tail rows per tile
#define NBLOCKS (N_ / NT)          // 2500
#define DPG     16                 // d's per group (16 groups)

// combined scale: x/(EMB_RANGE/PI) then /2 then rad->rev (/2pi) = x/(4*EMB_RANGE)
#define K2 4.571428571428571f

__device__ __forceinline__ float fract_(float x) { return __builtin_amdgcn_fractf(x); }
__device__ __forceinline__ float sinrev_(float x) { return __builtin_amdgcn_sinf(x); }

__global__ __launch_bounds__(512, 4)
void hake_kernel(const int* __restrict__ e1, const int* __restrict__ rel,
                 const float* __restrict__ emb_e, const float* __restrict__ emb_rel,
                 const float* __restrict__ pw_p, const float* __restrict__ mw_p,
                 float* __restrict__ out)
{
    __shared__ float2 tail[NT][D_];        // (phase_tail_rev, mod_tail) : 16 KB
    __shared__ float  red[8][2 * NT][32];  // per-wave partials          : 16 KB

    const int t    = threadIdx.x;
    const int b    = t & 31;      // batch index owned by this lane
    const int g    = t >> 5;      // d-group 0..15
    const int d_lo = g * DPG;
    const int w    = t >> 6;      // wave 0..7
    const int lane = t & 63;

    const float pw = pw_p[0];
    const float mw = mw_p[0];

    const int n0 = blockIdx.x * NT;

    // ---- issue tail loads early: wave w stages row n0+w (coalesced) --------
    const float* rowp = emb_e + (size_t)(n0 + w) * (2 * D_);
    float4 pv = *(const float4*)(rowp + lane * 4);
    float4 mv = *(const float4*)(rowp + D_ + lane * 4);

    // ---- per-thread tables for (b, d in [d_lo, d_lo+16)) -------------------
    float ar[DPG], mh[DPG], cc[DPG];
    {
        const int he = e1[b];
        const int hr = rel[b];
        const float* be = emb_e + (size_t)he * (2 * D_);
        const float* br = emb_rel + (size_t)hr * (3 * D_);
#pragma unroll
        for (int ii = 0; ii < 4; ++ii) {
            float4 ph4 = *(const float4*)(be + d_lo + ii * 4);
            float4 mh4 = *(const float4*)(be + D_ + d_lo + ii * 4);
            float4 pr4 = *(const float4*)(br + d_lo + ii * 4);
            float4 mr4 = *(const float4*)(br + D_ + d_lo + ii * 4);
            float4 bi4 = *(const float4*)(br + 2 * D_ + d_lo + ii * 4);
            float phv[4] = {ph4.x, ph4.y, ph4.z, ph4.w};
            float mhv[4] = {mh4.x, mh4.y, mh4.z, mh4.w};
            float prv[4] = {pr4.x, pr4.y, pr4.z, pr4.w};
            float mrv[4] = {mr4.x, mr4.y, mr4.z, mr4.w};
            float biv[4] = {bi4.x, bi4.y, bi4.z, bi4.w};
#pragma unroll
            for (int k = 0; k < 4; ++k) {
                const int i = ii * 4 + k;
                float mr = fabsf(mrv[k]);
                float bi = fminf(biv[k], 1.0f);
                bi = (bi < -mr) ? -mr : bi;
                ar[i] = (phv[k] + prv[k]) * K2;   // revolutions for sin(x/2)
                mh[i] = mhv[k] * (mr + bi);
                cc[i] = 1.0f - bi;
            }
        }
    }

    // ---- write staged tail row to LDS (32B contiguous per lane) ------------
    {
        const int d0 = lane * 4;
        tail[w][d0 + 0] = make_float2(pv.x * K2, mv.x);
        tail[w][d0 + 1] = make_float2(pv.y * K2, mv.y);
        tail[w][d0 + 2] = make_float2(pv.z * K2, mv.z);
        tail[w][d0 + 3] = make_float2(pv.w * K2, mv.w);
    }
    __syncthreads();

    // ---- accumulate: 16 d x 8 n per thread ---------------------------------
    float sph[NT], srs[NT];
#pragma unroll
    for (int j = 0; j < NT; ++j) { sph[j] = 0.0f; srs[j] = 0.0f; }

    const float4* tl = (const float4*)(&tail[0][0]);
#pragma unroll
    for (int i = 0; i < DPG; i += 2) {
        const int base = (d_lo + i) >> 1;   // float4 index within a row
#pragma unroll
        for (int j = 0; j < NT; ++j) {
            float4 tv = tl[j * (D_ / 2) + base];  // broadcast within 32-lane group
            float a0 = ar[i] - tv.x;
            float s0 = sinrev_(fract_(a0));
            sph[j] += fabsf(s0);
            float r0 = fmaf(-tv.y, cc[i], mh[i]);
            srs[j] = fmaf(r0, r0, srs[j]);
            float a1 = ar[i + 1] - tv.z;
            float s1 = sinrev_(fract_(a1));
            sph[j] += fabsf(s1);
            float r1 = fmaf(-tv.w, cc[i + 1], mh[i + 1]);
            srs[j] = fmaf(r1, r1, srs[j]);
        }
    }

    // ---- reduce: pair of d-groups within wave, then 8 waves via LDS --------
#pragma unroll
    for (int j = 0; j < NT; ++j) {
        sph[j] += __shfl_xor(sph[j], 32, 64);
        srs[j] += __shfl_xor(srs[j], 32, 64);
    }
    if (lane < 32) {
#pragma unroll
        for (int j = 0; j < NT; ++j) {
            red[w][j][lane]      = sph[j];
            red[w][NT + j][lane] = srs[j];
        }
    }
    __syncthreads();

    // ---- finalize: thread t<256 -> (b=t>>3, n0 + (t&7)) --------------------
    if (t < 256) {
        const int j  = t & 7;
        const int bb = t >> 3;
        float pa = 0.0f, ra = 0.0f;
#pragma unroll
        for (int ww = 0; ww < 8; ++ww) {
            pa += red[ww][j][bb];
            ra += red[ww][NT + j][bb];
        }
        float z = fmaf(pa, pw, sqrtf(ra) * mw) - 12.0f;  // GAMMA=12
        out[(size_t)bb * N_ + (n0 + j)] = 1.0f / (1.0f + __expf(z));
    }
}

extern "C" void kernel_launch(void* const* d_in, const int* in_sizes, int n_in,
                              void* d_out, int out_size, void* d_ws, size_t ws_size,
                              hipStream_t stream)
{
    // inputs: 0:g 1:e1 2:rel 3:e2_multi(unused) 4:emb_e 5:emb_rel 6:phase_w 7:mod_w
    const int*   e1      = (const int*)d_in[1];
    const int*   rel     = (const int*)d_in[2];
    const float* emb_e   = (const float*)d_in[4];
    const float* emb_rel = (const float*)d_in[5];
    const float* pw      = (const float*)d_in[6];
    const float* mw      = (const float*)d_in[7];
    float* out = (float*)d_out;

    hipLaunchKernelGGL(hake_kernel, dim3(NBLOCKS), dim3(512), 0, stream,
                       e1, rel, emb_e, emb_rel, pw, mw, out);
}